// Round 9
// baseline (149.573 us; speedup 1.0000x reference)
//
#include <hip/hip_runtime.h>
#include <hip/hip_bf16.h>
#include <math.h>

#define BETA_INV 20.0f          // 1/0.05
#define BG_KNN   50
#define N_CAMS   6
#define CLS      2000
#define DIM      2048
#define BATCH    256
#define NPROXY   (N_CAMS * CLS)     // 12000
#define MASK_VAL -10000.0f

typedef __attribute__((ext_vector_type(8))) short short8;
typedef __attribute__((ext_vector_type(4))) float f32x4;

__device__ __forceinline__ uint2 cvt4(float4 v) {
    uint2 r;
    asm("v_cvt_pk_bf16_f32 %0, %1, %2" : "=v"(r.x) : "v"(v.x), "v"(v.y));
    asm("v_cvt_pk_bf16_f32 %0, %1, %2" : "=v"(r.y) : "v"(v.z), "v"(v.w));
    return r;
}

// ---------------- convert feats -> bf16 (256 blocks x 256 thr x 8 elems) ----------------
__global__ __launch_bounds__(256) void conv_a(const float* __restrict__ A,
                                              unsigned short* __restrict__ Ab)
{
    const int idx = blockIdx.x * 256 + threadIdx.x;       // 0..65535
    const float4* p = (const float4*)A + (size_t)idx * 2;
    float4 v0 = p[0], v1 = p[1];
    uint2 a = cvt4(v0), b = cvt4(v1);
    *(uint4*)(Ab + (size_t)idx * 8) = make_uint4(a.x, a.y, b.x, b.y);
}

// ---------------- GEMM, no LDS, no barriers: direct global->reg MFMA ----------------
// BM=64, BN=96; 256 thr = 4 waves (2x2), wave tile 32x48 (2x3 frags 16x16x32).
// B read as fp32 directly from mem (L2-resident per XCD via swizzle), cvt inline.
// 2-deep register pipeline per wave; waves run free (no __syncthreads at all).
#define GBM 64
#define GBN 96
#define NTT (DIM / 64)          // 32 K-steps

__global__ __launch_bounds__(256) void gemm_direct(const unsigned short* __restrict__ Ab, // [256][2048] bf16
                                                   const float* __restrict__ Bm,          // [12000][2048] f32
                                                   float* __restrict__ C)                 // [256][12000]
{
    const int tid = threadIdx.x;
    // bijective XCD chunk swizzle (nwg=500): 4 bm-sharers of each B panel adjacent per XCD
    const int bid = blockIdx.x;
    const int xcd = bid & 7, pos = bid >> 3;
    const int lid = (xcd < 4 ? xcd * 63 : 252 + (xcd - 4) * 62) + pos;
    const int bm = (lid & 3) * GBM;
    const int bn = (lid >> 2) * GBN;

    const int lane = tid & 63, wid = tid >> 6;
    const int wm = (wid >> 1) * 32;
    const int wn = (wid & 1) * 48;
    const int fr = lane & 15, kg = lane >> 4;

    // fragment base pointers (per-lane)
    const unsigned short* pa0 = Ab + (size_t)(bm + wm + fr) * DIM + kg * 8;
    const float*          pb0 = Bm + (size_t)(bn + wn + fr) * DIM + kg * 8;

    f32x4 acc[2][3];
#pragma unroll
    for (int i = 0; i < 2; ++i)
#pragma unroll
        for (int j = 0; j < 3; ++j) acc[i][j] = (f32x4){0.f, 0.f, 0.f, 0.f};

    short8 afA[2][2], afB[2][2];
    float4 bA[3][2][2], bB[3][2][2];

#define LOADA(DST, T) do {                                                                \
        _Pragma("unroll")                                                                 \
        for (int i = 0; i < 2; ++i)                                                       \
            _Pragma("unroll")                                                             \
            for (int ks = 0; ks < 2; ++ks)                                                \
                DST[i][ks] = *(const short8*)(pa0 + (size_t)i * 16 * DIM + ks * 32 + (T) * 64); \
    } while (0)

#define LOADB(DST, T) do {                                                                \
        _Pragma("unroll")                                                                 \
        for (int j = 0; j < 3; ++j)                                                       \
            _Pragma("unroll")                                                             \
            for (int ks = 0; ks < 2; ++ks)                                                \
                _Pragma("unroll")                                                         \
                for (int h = 0; h < 2; ++h)                                               \
                    DST[j][ks][h] = *(const float4*)(pb0 + (size_t)j * 16 * DIM + ks * 32 + (T) * 64 + h * 4); \
    } while (0)

#define MM(AF, BF) do {                                                                   \
        _Pragma("unroll")                                                                 \
        for (int ks = 0; ks < 2; ++ks)                                                    \
            _Pragma("unroll")                                                             \
            for (int j = 0; j < 3; ++j) {                                                 \
                uint2 lo = cvt4(BF[j][ks][0]);                                            \
                uint2 hi = cvt4(BF[j][ks][1]);                                            \
                short8 bf = __builtin_bit_cast(short8, make_uint4(lo.x, lo.y, hi.x, hi.y)); \
                _Pragma("unroll")                                                         \
                for (int i = 0; i < 2; ++i)                                               \
                    acc[i][j] = __builtin_amdgcn_mfma_f32_16x16x32_bf16(AF[i][ks], bf, acc[i][j], 0, 0, 0); \
            }                                                                             \
    } while (0)

    // prologue: stage 0 in flight
    LOADA(afA, 0); LOADB(bA, 0);

#pragma unroll 1
    for (int t = 0; t < NTT - 2; t += 2) {
        LOADA(afB, t + 1); LOADB(bB, t + 1);
        MM(afA, bA);
        LOADA(afA, t + 2); LOADB(bA, t + 2);
        MM(afB, bB);
    }
    // tail: t = NTT-2
    LOADA(afB, NTT - 1); LOADB(bB, NTT - 1);
    MM(afA, bA);
    MM(afB, bB);

#undef LOADA
#undef LOADB
#undef MM

    // epilogue: C/D layout col=lane&15, row=(lane>>4)*4+reg
#pragma unroll
    for (int i = 0; i < 2; ++i)
#pragma unroll
        for (int j = 0; j < 3; ++j)
#pragma unroll
            for (int r = 0; r < 4; ++r)
                C[(size_t)(bm + wm + i * 16 + kg * 4 + r) * NPROXY + (bn + wn + j * 16 + fr)] = acc[i][j][r];
}

// ---------------- per-sample, register-resident (512 thr, 6x float4 each) ----------------
__device__ __forceinline__ float block_sum_f(float x, volatile float* red8, int lane, int wid) {
#pragma unroll
    for (int off = 32; off; off >>= 1) x += __shfl_xor(x, off);
    if (lane == 0) red8[wid] = x;
    __syncthreads();
    float t = 0.f;
#pragma unroll
    for (int w = 0; w < 8; ++w) t += red8[w];
    __syncthreads();
    return t;
}
__device__ __forceinline__ float block_max_f(float x, volatile float* red8, int lane, int wid) {
#pragma unroll
    for (int off = 32; off; off >>= 1) x = fmaxf(x, __shfl_xor(x, off));
    if (lane == 0) red8[wid] = x;
    __syncthreads();
    float t = -1e30f;
#pragma unroll
    for (int w = 0; w < 8; ++w) t = fmaxf(t, red8[w]);
    __syncthreads();
    return t;
}
__device__ __forceinline__ int block_sum_i(int x, volatile int* red8, int lane, int wid) {
#pragma unroll
    for (int off = 32; off; off >>= 1) x += __shfl_xor(x, off);
    if (lane == 0) red8[wid] = x;
    __syncthreads();
    int t = 0;
#pragma unroll
    for (int w = 0; w < 8; ++w) t += red8[w];
    __syncthreads();
    return t;
}

__global__ __launch_bounds__(512) void per_sample(const float* __restrict__ sims,
                                                  const int* __restrict__ cams,
                                                  const int* __restrict__ labels,
                                                  float* __restrict__ ce_out,
                                                  float* __restrict__ assoc_out)
{
    __shared__ float redf[8];
    __shared__ int   redi[8];
    __shared__ float pos_sh[N_CAMS];
    __shared__ float sh_vlab;

    const int i    = blockIdx.x;
    const int tid  = threadIdx.x;
    const int lane = tid & 63;
    const int wid  = tid >> 6;
    const float* s = sims + (size_t)i * NPROXY;
    const int cc   = cams[i];
    const int lab  = labels[i];

    float4 v[6];
#pragma unroll
    for (int ii = 0; ii < 6; ++ii) {
        int q = tid + 512 * ii;
        if (q < NPROXY / 4) v[ii] = *(const float4*)(s + 4 * q);
        else v[ii] = make_float4(-1e30f, -1e30f, -1e30f, -1e30f);
    }

    const int plab = cc * CLS + lab;
    const int qlab = plab >> 2, clab = plab & 3;
#pragma unroll
    for (int ii = 0; ii < 6; ++ii) {
        if ((qlab >> 9) == ii && (qlab & 511) == tid) {
            float t = (clab == 0) ? v[ii].x : (clab == 1) ? v[ii].y : (clab == 2) ? v[ii].z : v[ii].w;
            sh_vlab = t;
        }
    }

    // ---- CE over own-camera block: q in [cc*500, cc*500+500) ----
    const int qlo = cc * 500, qhi = qlo + 500;
    float m = -1e30f;
#pragma unroll
    for (int ii = 0; ii < 6; ++ii) {
        int q = tid + 512 * ii;
        if (q >= qlo && q < qhi)
            m = fmaxf(m, fmaxf(fmaxf(v[ii].x, v[ii].y), fmaxf(v[ii].z, v[ii].w)));
    }
    const float smax = block_max_f(m, redf, lane, wid);
    float ls = 0.f;
#pragma unroll
    for (int ii = 0; ii < 6; ++ii) {
        int q = tid + 512 * ii;
        if (q >= qlo && q < qhi) {
            ls += __expf((v[ii].x - smax) * BETA_INV);
            ls += __expf((v[ii].y - smax) * BETA_INV);
            ls += __expf((v[ii].z - smax) * BETA_INV);
            ls += __expf((v[ii].w - smax) * BETA_INV);
        }
    }
    const float lsum = block_sum_f(ls, redf, lane, wid);
    if (tid == 0) ce_out[i] = logf(lsum) + (smax - sh_vlab) * BETA_INV;

    // ---- capture positives (rows j*2000+lab), mask in-register ----
#define DOPC(II, COMP, CIDX) { \
        int p = 4 * (tid + 512 * (II)) + (CIDX); \
        int r = p - lab; \
        if (r >= 0 && r <= (N_CAMS - 1) * CLS && (r % CLS) == 0) { \
            pos_sh[r / CLS] = v[II].COMP; \
            v[II].COMP = MASK_VAL; \
        } }
#pragma unroll
    for (int ii = 0; ii < 6; ++ii) {
        DOPC(ii, x, 0); DOPC(ii, y, 1); DOPC(ii, z, 2); DOPC(ii, w, 3);
    }
#undef DOPC
    __syncthreads();

    // ---- masked row max M1 ----
    float mm = -1e30f;
#pragma unroll
    for (int ii = 0; ii < 6; ++ii)
        mm = fmaxf(mm, fmaxf(fmaxf(v[ii].x, v[ii].y), fmaxf(v[ii].z, v[ii].w)));
    const float M1 = block_max_f(mm, redf, lane, wid);

    float pmax = -1e30f, psum = 0.f;
#pragma unroll
    for (int j = 0; j < N_CAMS; ++j) {
        float pv = pos_sh[j];
        pmax = fmaxf(pmax, pv);
        psum += pv;
    }

    // ---- 20-step bisection for 50th-largest (ties handled exactly below) ----
    float lo = M1 - 0.5f, hi = M1 + 1e-4f;
    int cnt_hi = 0;
    for (int it = 0; it < 20; ++it) {
        const float mid = 0.5f * (lo + hi);
        int c = 0;
#pragma unroll
        for (int ii = 0; ii < 6; ++ii) {
            c += (v[ii].x >= mid); c += (v[ii].y >= mid);
            c += (v[ii].z >= mid); c += (v[ii].w >= mid);
        }
        const int tot = block_sum_i(c, redi, lane, wid);
        if (tot >= BG_KNN) lo = mid; else { hi = mid; cnt_hi = tot; }
    }

    // ---- final: sum exp over the top-50 ----
    const float M = fmaxf(M1, pmax);
    float ss = 0.f, vt = -1e30f;
#pragma unroll
    for (int ii = 0; ii < 6; ++ii) {
#define DOF(COMP) { float x = v[ii].COMP; \
        if (x >= hi) ss += __expf((x - M) * BETA_INV); \
        else if (x >= lo) vt = fmaxf(vt, x); }
        DOF(x) DOF(y) DOF(z) DOF(w)
#undef DOF
    }
    const float ssum = block_sum_f(ss, redf, lane, wid);
    const float vtie = block_max_f(vt, redf, lane, wid);

    if (tid == 0) {
        int need = BG_KNN - cnt_hi;
        float vts = (vtie < -1e29f) ? lo : vtie;
        float total = ssum + (float)need * __expf((vts - M) * BETA_INV);
#pragma unroll
        for (int j = 0; j < N_CAMS; ++j) total += __expf((pos_sh[j] - M) * BETA_INV);
        assoc_out[i] = M * BETA_INV + logf(total) - psum * BETA_INV / (float)N_CAMS;
    }
}

// ---------------- Finalize: parallel per-camera segment means -> scalar loss ----------------
__global__ __launch_bounds__(256) void finalize(const int* __restrict__ cams,
                                                const float* __restrict__ ce,
                                                const float* __restrict__ assoc,
                                                float* __restrict__ out)
{
    __shared__ float ce_s[N_CAMS], as_s[N_CAMS];
    __shared__ int   cnt[N_CAMS];
    const int tid = threadIdx.x;
    if (tid < N_CAMS) { ce_s[tid] = 0.f; as_s[tid] = 0.f; cnt[tid] = 0; }
    __syncthreads();
    const int c = cams[tid];
    atomicAdd(&ce_s[c], ce[tid]);
    atomicAdd(&as_s[c], assoc[tid]);
    atomicAdd(&cnt[c], 1);
    __syncthreads();
    if (tid == 0) {
        float loss = 0.f;
        for (int k = 0; k < N_CAMS; ++k) {
            if (cnt[k] > 0) {
                float inv = 1.f / (float)cnt[k];
                loss += ce_s[k] * inv + 0.5f * as_s[k] * inv;
            }
        }
        out[0] = loss;
    }
}

extern "C" void kernel_launch(void* const* d_in, const int* in_sizes, int n_in,
                              void* d_out, int out_size, void* d_ws, size_t ws_size,
                              hipStream_t stream) {
    const float* feats  = (const float*)d_in[0];   // [256][2048]
    const float* mem    = (const float*)d_in[1];   // [6][2000][2048]
    const int*   cams   = (const int*)d_in[2];
    const int*   labels = (const int*)d_in[3];
    float* out = (float*)d_out;

    float* sims  = (float*)d_ws;                                // 12.29 MB
    float* ce    = sims + (size_t)BATCH * NPROXY;
    float* assoc = ce + BATCH;
    unsigned short* A_bf = (unsigned short*)(assoc + BATCH);    // 1 MB

    conv_a<<<256, 256, 0, stream>>>(feats, A_bf);
    gemm_direct<<<500, 256, 0, stream>>>(A_bf, mem, sims);
    per_sample<<<BATCH, 512, 0, stream>>>(sims, cams, labels, ce, assoc);
    finalize<<<1, 256, 0, stream>>>(cams, ce, assoc, out);
}

// Round 10
// 84.855 us; speedup vs baseline: 1.7627x; 1.7627x over previous
//
#include <hip/hip_runtime.h>
#include <hip/hip_bf16.h>
#include <math.h>

#define BETA_INV 20.0f          // 1/0.05
#define BG_KNN   50
#define N_CAMS   6
#define CLS      2000
#define DIM      2048
#define BATCH    256
#define NPROXY   (N_CAMS * CLS)     // 12000
#define MASK_VAL -10000.0f

typedef __attribute__((ext_vector_type(8))) short short8;
typedef __attribute__((ext_vector_type(4))) float f32x4;
typedef __attribute__((address_space(1))) const unsigned int g_u32;
typedef __attribute__((address_space(3))) unsigned int l_u32;

#define S_(x) #x
#define SX(x) S_(x)

__device__ __forceinline__ uint2 cvt4(float4 v) {
    uint2 r;
    asm("v_cvt_pk_bf16_f32 %0, %1, %2" : "=v"(r.x) : "v"(v.x), "v"(v.y));
    asm("v_cvt_pk_bf16_f32 %0, %1, %2" : "=v"(r.y) : "v"(v.z), "v"(v.w));
    return r;
}

// ---------------- convert feats -> bf16 (256 blocks x 256 thr x 8 elems) ----------------
__global__ __launch_bounds__(256) void conv_a(const float* __restrict__ A,
                                              unsigned short* __restrict__ Ab)
{
    const int idx = blockIdx.x * 256 + threadIdx.x;       // 0..65535
    const float4* p = (const float4*)A + (size_t)idx * 2;
    float4 v0 = p[0], v1 = p[1];
    uint2 a = cvt4(v0), b = cvt4(v1);
    *(uint4*)(Ab + (size_t)idx * 8) = make_uint4(a.x, a.y, b.x, b.y);
}

// ---------------- GEMM: sims = A_bf16 @ mem^T.  B fp32 staged via global_load_lds ----
// BM=64, BN=96, BK=32; 256 thr = 4 waves (2x2), wave tile 32x48 (2x3 frags 16x16x32).
// 4-buffer LDS ring, 3-deep prefetch, counted per-wave vmcnt(10). Source-side XOR
// swizzle (c4 ^= row&7) -> conflict-spread b128 reads. cvt fp32->bf16 on LDS read.
#define GBM 64
#define GBN 96
#define GBK 32
#define NTT (DIM / GBK)         // 64 K-steps

__global__ __launch_bounds__(256, 3) void gemm_mfma(const unsigned short* __restrict__ Ab, // [256][2048] bf16
                                                    const float* __restrict__ Bm,          // [12000][2048] f32
                                                    float* __restrict__ C)                 // [256][12000]
{
    __shared__ __align__(16) float Bs[4][3072];   // 4 x 12KB ring

    const int tid = threadIdx.x;
    // bijective XCD chunk swizzle (nwg=500): 4 bm-sharers of each B panel adjacent per XCD
    const int bid = blockIdx.x;
    const int xcd = bid & 7, pos = bid >> 3;
    const int lid = (xcd < 4 ? xcd * 63 : 252 + (xcd - 4) * 62) + pos;
    const int bm = (lid & 3) * GBM;
    const int bn = (lid >> 2) * GBN;

    const int lane = tid & 63, wid = tid >> 6;
    const int wm = (wid >> 1) * 32;
    const int wn = (wid & 1) * 48;
    const int fr = lane & 15, kg = lane >> 4;

    // A fragment pointers (bf16, L2-resident): pa[i] + T*32
    const unsigned short* pa[2];
#pragma unroll
    for (int i = 0; i < 2; ++i)
        pa[i] = Ab + (size_t)(bm + wm + i * 16 + fr) * DIM + kg * 8;

    // B stage source (per-thread, swizzled): thread t covers row r8=t>>3 (+32q),
    // global 16B-chunk c4 = (t&7) ^ (r8&7); LDS dest linear tid*16 per 4KB round.
    const int r8  = tid >> 3;
    const int c4s = tid & 7;
    const float* pbsrc = Bm + (size_t)(bn + r8) * DIM + ((c4s ^ (r8 & 7)) * 4);

    // frag read byte-offsets (lane constants): row R=wn+j*16+fr, chunks (2kg)^x,(2kg+1)^x
    const int x7 = fr & 7;
    int off0[3], off1[3];
#pragma unroll
    for (int j = 0; j < 3; ++j) {
        const int rb = (wn + j * 16 + fr) * 128;
        off0[j] = rb + (((2 * kg) ^ x7) << 4);
        off1[j] = rb + (((2 * kg + 1) ^ x7) << 4);
    }

    f32x4 acc[2][3];
#pragma unroll
    for (int i = 0; i < 2; ++i)
#pragma unroll
        for (int j = 0; j < 3; ++j) acc[i][j] = (f32x4){0.f, 0.f, 0.f, 0.f};

    short8 af[4][2];   // 4-slot A pipeline (all indices static)

#define STAGE(BUFI, T) do {                                                               \
        _Pragma("unroll")                                                                 \
        for (int q = 0; q < 3; ++q) {                                                     \
            const float* gp = pbsrc + (size_t)q * 32 * DIM + (T) * GBK;                   \
            __builtin_amdgcn_global_load_lds((g_u32*)gp,                                  \
                (l_u32*)&Bs[BUFI][q * 1024 + tid * 4], 16, 0, 0);                         \
        }                                                                                 \
    } while (0)

#define LOADA(SLOT, T) do {                                                               \
        _Pragma("unroll")                                                                 \
        for (int i = 0; i < 2; ++i)                                                       \
            af[SLOT][i] = *(const short8*)(pa[i] + (T) * GBK);                            \
    } while (0)

    // ---- prologue: 3 tiles in flight ----
    STAGE(0, 0); LOADA(0, 0);
    STAGE(1, 1); LOADA(1, 1);
    STAGE(2, 2); LOADA(2, 2);

#define BODY(K, T, VMC, DOISSUE) do {                                                     \
    asm volatile("s_waitcnt vmcnt(" SX(VMC) ")" ::: "memory");                            \
    __builtin_amdgcn_sched_barrier(0);                                                    \
    __builtin_amdgcn_s_barrier();                                                         \
    __builtin_amdgcn_sched_barrier(0);                                                    \
    if (DOISSUE) {                                                                        \
        STAGE((K + 3) & 3, (T) + 3);                                                      \
        LOADA((K + 3) & 3, (T) + 3);                                                      \
        __builtin_amdgcn_sched_barrier(0);                                                \
    }                                                                                     \
    _Pragma("unroll")                                                                     \
    for (int j = 0; j < 3; ++j) {                                                         \
        float4 lo = *(const float4*)((const char*)&Bs[K][0] + off0[j]);                   \
        float4 hi = *(const float4*)((const char*)&Bs[K][0] + off1[j]);                   \
        uint2 ca = cvt4(lo), cb = cvt4(hi);                                               \
        short8 bf = __builtin_bit_cast(short8, make_uint4(ca.x, ca.y, cb.x, cb.y));       \
        _Pragma("unroll")                                                                 \
        for (int i = 0; i < 2; ++i)                                                       \
            acc[i][j] = __builtin_amdgcn_mfma_f32_16x16x32_bf16(af[K][i], bf, acc[i][j], 0, 0, 0); \
    }                                                                                     \
} while (0)

    for (int tt = 0; tt < 60; tt += 4) {
        BODY(0, tt + 0, 10, 1);
        BODY(1, tt + 1, 10, 1);
        BODY(2, tt + 2, 10, 1);
        BODY(3, tt + 3, 10, 1);
    }
    // tail: bodies 60..63
    BODY(0, 60, 10, 1);    // issues tile 63 -> buf3/af3
    BODY(1, 61, 10, 0);
    BODY(2, 62, 5, 0);
    BODY(3, 63, 0, 0);
#undef BODY
#undef STAGE
#undef LOADA

    // epilogue: C/D layout col=lane&15, row=(lane>>4)*4+reg
#pragma unroll
    for (int i = 0; i < 2; ++i)
#pragma unroll
        for (int j = 0; j < 3; ++j)
#pragma unroll
            for (int r = 0; r < 4; ++r)
                C[(size_t)(bm + wm + i * 16 + kg * 4 + r) * NPROXY + (bn + wn + j * 16 + fr)] = acc[i][j][r];
}

// ---------------- per-sample, register-resident (512 thr, 6x float4 each) ----------------
__device__ __forceinline__ float block_sum_f(float x, volatile float* red8, int lane, int wid) {
#pragma unroll
    for (int off = 32; off; off >>= 1) x += __shfl_xor(x, off);
    if (lane == 0) red8[wid] = x;
    __syncthreads();
    float t = 0.f;
#pragma unroll
    for (int w = 0; w < 8; ++w) t += red8[w];
    __syncthreads();
    return t;
}
__device__ __forceinline__ float block_max_f(float x, volatile float* red8, int lane, int wid) {
#pragma unroll
    for (int off = 32; off; off >>= 1) x = fmaxf(x, __shfl_xor(x, off));
    if (lane == 0) red8[wid] = x;
    __syncthreads();
    float t = -1e30f;
#pragma unroll
    for (int w = 0; w < 8; ++w) t = fmaxf(t, red8[w]);
    __syncthreads();
    return t;
}
__device__ __forceinline__ int block_sum_i(int x, volatile int* red8, int lane, int wid) {
#pragma unroll
    for (int off = 32; off; off >>= 1) x += __shfl_xor(x, off);
    if (lane == 0) red8[wid] = x;
    __syncthreads();
    int t = 0;
#pragma unroll
    for (int w = 0; w < 8; ++w) t += red8[w];
    __syncthreads();
    return t;
}

__global__ __launch_bounds__(512) void per_sample(const float* __restrict__ sims,
                                                  const int* __restrict__ cams,
                                                  const int* __restrict__ labels,
                                                  float* __restrict__ ce_out,
                                                  float* __restrict__ assoc_out)
{
    __shared__ float redf[8];
    __shared__ int   redi[8];
    __shared__ float pos_sh[N_CAMS];
    __shared__ float sh_vlab;

    const int i    = blockIdx.x;
    const int tid  = threadIdx.x;
    const int lane = tid & 63;
    const int wid  = tid >> 6;
    const float* s = sims + (size_t)i * NPROXY;
    const int cc   = cams[i];
    const int lab  = labels[i];

    float4 v[6];
#pragma unroll
    for (int ii = 0; ii < 6; ++ii) {
        int q = tid + 512 * ii;
        if (q < NPROXY / 4) v[ii] = *(const float4*)(s + 4 * q);
        else v[ii] = make_float4(-1e30f, -1e30f, -1e30f, -1e30f);
    }

    const int plab = cc * CLS + lab;
    const int qlab = plab >> 2, clab = plab & 3;
#pragma unroll
    for (int ii = 0; ii < 6; ++ii) {
        if ((qlab >> 9) == ii && (qlab & 511) == tid) {
            float t = (clab == 0) ? v[ii].x : (clab == 1) ? v[ii].y : (clab == 2) ? v[ii].z : v[ii].w;
            sh_vlab = t;
        }
    }

    // ---- CE over own-camera block: q in [cc*500, cc*500+500) ----
    const int qlo = cc * 500, qhi = qlo + 500;
    float m = -1e30f;
#pragma unroll
    for (int ii = 0; ii < 6; ++ii) {
        int q = tid + 512 * ii;
        if (q >= qlo && q < qhi)
            m = fmaxf(m, fmaxf(fmaxf(v[ii].x, v[ii].y), fmaxf(v[ii].z, v[ii].w)));
    }
    const float smax = block_max_f(m, redf, lane, wid);
    float ls = 0.f;
#pragma unroll
    for (int ii = 0; ii < 6; ++ii) {
        int q = tid + 512 * ii;
        if (q >= qlo && q < qhi) {
            ls += __expf((v[ii].x - smax) * BETA_INV);
            ls += __expf((v[ii].y - smax) * BETA_INV);
            ls += __expf((v[ii].z - smax) * BETA_INV);
            ls += __expf((v[ii].w - smax) * BETA_INV);
        }
    }
    const float lsum = block_sum_f(ls, redf, lane, wid);
    if (tid == 0) ce_out[i] = logf(lsum) + (smax - sh_vlab) * BETA_INV;

    // ---- capture positives (rows j*2000+lab), mask in-register ----
#define DOPC(II, COMP, CIDX) { \
        int p = 4 * (tid + 512 * (II)) + (CIDX); \
        int r = p - lab; \
        if (r >= 0 && r <= (N_CAMS - 1) * CLS && (r % CLS) == 0) { \
            pos_sh[r / CLS] = v[II].COMP; \
            v[II].COMP = MASK_VAL; \
        } }
#pragma unroll
    for (int ii = 0; ii < 6; ++ii) {
        DOPC(ii, x, 0); DOPC(ii, y, 1); DOPC(ii, z, 2); DOPC(ii, w, 3);
    }
#undef DOPC
    __syncthreads();

    // ---- masked row max M1 ----
    float mm = -1e30f;
#pragma unroll
    for (int ii = 0; ii < 6; ++ii)
        mm = fmaxf(mm, fmaxf(fmaxf(v[ii].x, v[ii].y), fmaxf(v[ii].z, v[ii].w)));
    const float M1 = block_max_f(mm, redf, lane, wid);

    float pmax = -1e30f, psum = 0.f;
#pragma unroll
    for (int j = 0; j < N_CAMS; ++j) {
        float pv = pos_sh[j];
        pmax = fmaxf(pmax, pv);
        psum += pv;
    }

    // ---- 20-step bisection for 50th-largest (ties handled exactly below) ----
    float lo = M1 - 0.5f, hi = M1 + 1e-4f;
    int cnt_hi = 0;
    for (int it = 0; it < 20; ++it) {
        const float mid = 0.5f * (lo + hi);
        int c = 0;
#pragma unroll
        for (int ii = 0; ii < 6; ++ii) {
            c += (v[ii].x >= mid); c += (v[ii].y >= mid);
            c += (v[ii].z >= mid); c += (v[ii].w >= mid);
        }
        const int tot = block_sum_i(c, redi, lane, wid);
        if (tot >= BG_KNN) lo = mid; else { hi = mid; cnt_hi = tot; }
    }

    // ---- final: sum exp over the top-50 ----
    const float M = fmaxf(M1, pmax);
    float ss = 0.f, vt = -1e30f;
#pragma unroll
    for (int ii = 0; ii < 6; ++ii) {
#define DOF(COMP) { float x = v[ii].COMP; \
        if (x >= hi) ss += __expf((x - M) * BETA_INV); \
        else if (x >= lo) vt = fmaxf(vt, x); }
        DOF(x) DOF(y) DOF(z) DOF(w)
#undef DOF
    }
    const float ssum = block_sum_f(ss, redf, lane, wid);
    const float vtie = block_max_f(vt, redf, lane, wid);

    if (tid == 0) {
        int need = BG_KNN - cnt_hi;
        float vts = (vtie < -1e29f) ? lo : vtie;
        float total = ssum + (float)need * __expf((vts - M) * BETA_INV);
#pragma unroll
        for (int j = 0; j < N_CAMS; ++j) total += __expf((pos_sh[j] - M) * BETA_INV);
        assoc_out[i] = M * BETA_INV + logf(total) - psum * BETA_INV / (float)N_CAMS;
    }
}

// ---------------- Finalize: parallel per-camera segment means -> scalar loss ----------------
__global__ __launch_bounds__(256) void finalize(const int* __restrict__ cams,
                                                const float* __restrict__ ce,
                                                const float* __restrict__ assoc,
                                                float* __restrict__ out)
{
    __shared__ float ce_s[N_CAMS], as_s[N_CAMS];
    __shared__ int   cnt[N_CAMS];
    const int tid = threadIdx.x;
    if (tid < N_CAMS) { ce_s[tid] = 0.f; as_s[tid] = 0.f; cnt[tid] = 0; }
    __syncthreads();
    const int c = cams[tid];
    atomicAdd(&ce_s[c], ce[tid]);
    atomicAdd(&as_s[c], assoc[tid]);
    atomicAdd(&cnt[c], 1);
    __syncthreads();
    if (tid == 0) {
        float loss = 0.f;
        for (int k = 0; k < N_CAMS; ++k) {
            if (cnt[k] > 0) {
                float inv = 1.f / (float)cnt[k];
                loss += ce_s[k] * inv + 0.5f * as_s[k] * inv;
            }
        }
        out[0] = loss;
    }
}

extern "C" void kernel_launch(void* const* d_in, const int* in_sizes, int n_in,
                              void* d_out, int out_size, void* d_ws, size_t ws_size,
                              hipStream_t stream) {
    const float* feats  = (const float*)d_in[0];   // [256][2048]
    const float* mem    = (const float*)d_in[1];   // [6][2000][2048]
    const int*   cams   = (const int*)d_in[2];
    const int*   labels = (const int*)d_in[3];
    float* out = (float*)d_out;

    float* sims  = (float*)d_ws;                                // 12.29 MB
    float* ce    = sims + (size_t)BATCH * NPROXY;
    float* assoc = ce + BATCH;
    unsigned short* A_bf = (unsigned short*)(assoc + BATCH);    // 1 MB

    conv_a<<<256, 256, 0, stream>>>(feats, A_bf);
    gemm_mfma<<<500, 256, 0, stream>>>(A_bf, mem, sims);
    per_sample<<<BATCH, 512, 0, stream>>>(sims, cams, labels, ce, assoc);
    finalize<<<1, 256, 0, stream>>>(cams, ce, assoc, out);
}